// Round 5
// baseline (213.206 us; speedup 1.0000x reference)
//
#include <hip/hip_runtime.h>
#include <hip/hip_bf16.h>

typedef __attribute__((ext_vector_type(8))) short bf16x8;
typedef __attribute__((ext_vector_type(4))) float f32x4;

__device__ __forceinline__ float bf2f(unsigned short u) {
    union { unsigned int i; float f; } c; c.i = ((unsigned int)u) << 16; return c.f;
}
__device__ __forceinline__ unsigned short f2bf(float f) {
    union { float f; unsigned int i; } c; c.f = f;
    unsigned int x = c.i;
    x += 0x7fffu + ((x >> 16) & 1u);   // round-to-nearest-even
    return (unsigned short)(x >> 16);
}
__device__ __forceinline__ float tanh_fast(float v) {
    float a = fabsf(v);
    a = fminf(a, 15.0f);
    float e = __expf(2.0f * a);
    float t = 1.0f - 2.0f / (e + 1.0f);
    return copysignf(t, v);
}

// async global->LDS, 16B per lane; lptr must be wave-uniform, gptr per-lane
#define GLOAD_LDS16(gp, lp) \
    __builtin_amdgcn_global_load_lds((const __attribute__((address_space(1))) void*)(gp), \
                                     (__attribute__((address_space(3))) void*)(lp), 16, 0, 0)

#define MFMA(a, b, c) __builtin_amdgcn_mfma_f32_16x16x32_bf16((a), (b), (c), 0, 0, 0)

#define SBAR()  __builtin_amdgcn_s_barrier()
#define SCHED0() __builtin_amdgcn_sched_barrier(0)

// ---------------- small reductions ----------------

// sum over t of x -> sumx[b][d] (atomic partials; sumx pre-zeroed)
__global__ void k_sumx(const float* __restrict__ x, float* __restrict__ sumx) {
    int b = blockIdx.x, tc = blockIdx.y;
    int tid = threadIdx.x;
    const float* xp = x + ((size_t)b * 1024 + tc * 64) * 512;
    float a0 = 0.f, a1 = 0.f;
    for (int t = 0; t < 64; ++t) {
        a0 += xp[(size_t)t * 512 + tid];
        a1 += xp[(size_t)t * 512 + tid + 256];
    }
    atomicAdd(&sumx[b * 512 + tid], a0);
    atomicAdd(&sumx[b * 512 + tid + 256], a1);
}

// Abf[i][k] = bf16(m1w[i][k]) (natural order; K index k = e*8+s), fused with
// bias2[i] = sum_k m1w[i,k] * b_ent[(k&7)*512 + (k>>3)]
__global__ void k_prepA(const float* __restrict__ m1w, const float* __restrict__ bent,
                        unsigned short* __restrict__ Abf, float* __restrict__ bias2) {
    int i = blockIdx.x, tid = threadIdx.x;
    const float* row = m1w + (size_t)i * 4096;
    float acc = 0.f;
    #pragma unroll
    for (int q = 0; q < 4; ++q) {
        int col = q * 1024 + tid * 4;
        float4 v = *(const float4*)(row + col);
        ushort4 o;
        o.x = f2bf(v.x); o.y = f2bf(v.y); o.z = f2bf(v.z); o.w = f2bf(v.w);
        *(ushort4*)(Abf + (size_t)i * 4096 + col) = o;
        int e0 = col >> 3, s0 = col & 7;
        acc += v.x * bent[(s0    ) * 512 + e0];
        acc += v.y * bent[(s0 + 1) * 512 + e0];
        acc += v.z * bent[(s0 + 2) * 512 + e0];
        acc += v.w * bent[(s0 + 3) * 512 + e0];
    }
    #pragma unroll
    for (int off = 32; off; off >>= 1) acc += __shfl_xor(acc, off);
    __shared__ float r4[4];
    if ((tid & 63) == 0) r4[tid >> 6] = acc;
    __syncthreads();
    if (tid == 0) bias2[i] = r4[0] + r4[1] + r4[2] + r4[3];
}

// WT[j][k] = bf16(W_ent[(k&7)*512 + (k>>3)][j]); k = e*8+s
__global__ void k_conv_W(const float* __restrict__ W, unsigned short* __restrict__ WT) {
    __shared__ float tile[128][33];
    int e0 = blockIdx.x * 16;
    int j0 = blockIdx.y * 32;
    int tid = threadIdx.x;
    int tx = tid & 31, ty = tid >> 5;
    #pragma unroll
    for (int q = 0; q < 16; ++q) {
        int lk = q * 8 + ty;
        int de = lk >> 3, s = lk & 7;
        int r = s * 512 + e0 + de;
        tile[lk][tx] = W[(size_t)r * 1024 + j0 + tx];
    }
    __syncthreads();
    int j = tid >> 3, ck = (tid & 7) * 16;
    unsigned short* dst = WT + (size_t)(j0 + j) * 4096 + e0 * 8 + ck;
    #pragma unroll
    for (int g = 0; g < 4; ++g) {
        ushort4 o;
        o.x = f2bf(tile[ck + g * 4 + 0][j]);
        o.y = f2bf(tile[ck + g * 4 + 1][j]);
        o.z = f2bf(tile[ck + g * 4 + 2][j]);
        o.w = f2bf(tile[ck + g * 4 + 3][j]);
        *(ushort4*)(dst + g * 4) = o;
    }
}

// ---------------- GEMM1 (split-K=8, pipelined): C[i,j] = sum_k Abf[i,k] WT[j,k] ----------------
__launch_bounds__(512, 2)
__global__ void k_gemm1(const unsigned short* __restrict__ Abf,
                        const unsigned short* __restrict__ WT,
                        float* __restrict__ CpL, float* __restrict__ CpR) {
    __shared__ __align__(16) unsigned short sA[2][64 * 64];
    __shared__ __align__(16) unsigned short sB[2][256 * 64];
    int i0 = blockIdx.x * 64;
    int j0 = blockIdx.y * 256;
    int kbase = blockIdx.z * 512;
    int tid = threadIdx.x, lane = tid & 63, w = tid >> 6;
    int wm = w >> 2, wn = w & 3;
    int lr = lane >> 3, sl = lane & 7;
    int lo = lane & 15, hi = lane >> 4;
    int arow = w * 8 + lr;
    const unsigned short* gA = Abf + (size_t)(i0 + arow) * 4096 + kbase + ((sl ^ lr) << 3);
    const unsigned short* gB0 = WT + (size_t)(j0 + w * 32 + 0 * 8 + lr) * 4096 + kbase + ((sl ^ lr) << 3);
    const unsigned short* gB1 = WT + (size_t)(j0 + w * 32 + 1 * 8 + lr) * 4096 + kbase + ((sl ^ lr) << 3);
    const unsigned short* gB2 = WT + (size_t)(j0 + w * 32 + 2 * 8 + lr) * 4096 + kbase + ((sl ^ lr) << 3);
    const unsigned short* gB3 = WT + (size_t)(j0 + w * 32 + 3 * 8 + lr) * 4096 + kbase + ((sl ^ lr) << 3);
    bool left = (blockIdx.y < 2);
    f32x4 acc[2][4] = {};

#define G1_STAGE(tt, bufn)                                                    \
    do {                                                                      \
        int koff = (tt) * 64;                                                 \
        GLOAD_LDS16(gA + koff, &sA[bufn][w * 8 * 64]);                        \
        GLOAD_LDS16(gB0 + koff, &sB[bufn][(w * 32 + 0) * 64]);                \
        GLOAD_LDS16(gB1 + koff, &sB[bufn][(w * 32 + 8) * 64]);                \
        GLOAD_LDS16(gB2 + koff, &sB[bufn][(w * 32 + 16) * 64]);               \
        GLOAD_LDS16(gB3 + koff, &sB[bufn][(w * 32 + 24) * 64]);               \
        SCHED0();                                                             \
    } while (0)

    G1_STAGE(0, 0);
    #pragma unroll
    for (int t = 0; t < 8; ++t) {
        int buf = t & 1;
        if (t < 7) {
            G1_STAGE(t + 1, buf ^ 1);
            asm volatile("s_waitcnt vmcnt(5)" ::: "memory");
        } else {
            asm volatile("s_waitcnt vmcnt(0)" ::: "memory");
        }
        SCHED0(); SBAR(); SCHED0();
        __builtin_amdgcn_s_setprio(1);
        #pragma unroll
        for (int kk = 0; kk < 2; ++kk) {
            int slotX = ((kk * 4 + hi) ^ (lo & 7)) << 3;
            bf16x8 a0 = *(const bf16x8*)(&sA[buf][(wm * 32 +      lo) * 64 + slotX]);
            bf16x8 a1 = *(const bf16x8*)(&sA[buf][(wm * 32 + 16 + lo) * 64 + slotX]);
            #pragma unroll
            for (int n = 0; n < 4; ++n) {
                bf16x8 bb = *(const bf16x8*)(&sB[buf][(wn * 64 + n * 16 + lo) * 64 + slotX]);
                if (left) {
                    acc[0][n] = MFMA(a0, bb, acc[0][n]);
                    acc[1][n] = MFMA(a1, bb, acc[1][n]);
                } else {
                    acc[0][n] = MFMA(bb, a0, acc[0][n]);
                    acc[1][n] = MFMA(bb, a1, acc[1][n]);
                }
            }
        }
        __builtin_amdgcn_s_setprio(0);
        if (t < 7) { SCHED0(); SBAR(); SCHED0(); }
    }
#undef G1_STAGE

    int ksoff = blockIdx.z * 262144;
    if (left) {
        #pragma unroll
        for (int m = 0; m < 2; ++m) {
            int ib = i0 + wm * 32 + m * 16 + hi * 4;
            #pragma unroll
            for (int n = 0; n < 4; ++n) {
                int j = j0 + wn * 64 + n * 16 + lo;
                #pragma unroll
                for (int r = 0; r < 4; ++r)
                    CpL[ksoff + (ib + r) * 512 + j] = acc[m][n][r];
            }
        }
    } else {
        #pragma unroll
        for (int m = 0; m < 2; ++m) {
            int ic = i0 + wm * 32 + m * 16 + lo;
            #pragma unroll
            for (int n = 0; n < 4; ++n) {
                int db = j0 - 512 + wn * 64 + n * 16 + hi * 4;
                #pragma unroll
                for (int r = 0; r < 4; ++r)
                    CpR[ksoff + (db + r) * 512 + ic] = acc[m][n][r];
            }
        }
    }
}

// sum 8 split-K partials -> bf16; blocks 0..255 -> M1bf (row-major), 256..511 -> M2t
__global__ void k_reduce(const float* __restrict__ CpL, const float* __restrict__ CpR,
                         unsigned short* __restrict__ M1bf, unsigned short* __restrict__ M2t) {
    int bx = blockIdx.x;
    const float* Cp = (bx < 256) ? CpL : CpR;
    unsigned short* ob = (bx < 256) ? M1bf : M2t;
    int gid = (bx & 255) * 256 + threadIdx.x;
    float4 s = ((const float4*)Cp)[gid];
    #pragma unroll
    for (int ks = 1; ks < 8; ++ks) {
        float4 t = ((const float4*)Cp)[ks * 65536 + gid];
        s.x += t.x; s.y += t.y; s.z += t.z; s.w += t.w;
    }
    ushort4 o;
    o.x = f2bf(s.x); o.y = f2bf(s.y); o.z = f2bf(s.z); o.w = f2bf(s.w);
    ((ushort4*)ob)[gid] = o;
}

// cb[b][i] = (1/T) * sum_d sumx[b][d]*M2t[d][i] + bias2[i] + m1b[i]
__global__ void k_cb(const float* __restrict__ sumx, const unsigned short* __restrict__ M2t,
                     const float* __restrict__ bias2, const float* __restrict__ m1b,
                     float* __restrict__ cbo) {
    int b = blockIdx.x, i0 = blockIdx.y * 64;
    int tid = threadIdx.x;
    int il = tid & 63, dq = tid >> 6;
    const float* sx = sumx + b * 512 + dq * 128;
    const unsigned short* mp = M2t + (size_t)dq * 128 * 512 + i0 + il;
    float acc = 0.f;
    #pragma unroll 4
    for (int dd = 0; dd < 128; ++dd)
        acc += sx[dd] * bf2f(mp[(size_t)dd * 512]);
    __shared__ float sPart[4][64];
    sPart[dq][il] = acc;
    __syncthreads();
    if (tid < 64) {
        float v = sPart[0][tid] + sPart[1][tid] + sPart[2][tid] + sPart[3][tid];
        cbo[b * 512 + i0 + tid] = v * (1.0f / 1024.0f) + bias2[i0 + tid] + m1b[i0 + tid];
    }
}

// ================= DIAGNOSTIC PROBES (outputs dead; timing only) =================

// PROBE 1: compute-only. Stage LDS once, then 16 reps of the 8-phase MFMA loop.
__launch_bounds__(512)
__global__ void k_probe_comp(const float* __restrict__ x,
                             const unsigned short* __restrict__ M1bf,
                             float* __restrict__ scratch) {
    __shared__ __align__(16) unsigned short sA[64 * 64];
    __shared__ __align__(16) unsigned short sB[512 * 64];
    int bt0 = blockIdx.x * 64;
    int tid = threadIdx.x, lane = tid & 63, w = tid >> 6;
    int wm = w >> 2, wn = w & 3;
    int lo = lane & 15, hi = lane >> 4;
    int lr = lane >> 3, sl = lane & 7;
    int arow = tid >> 3, aslot = tid & 7;
    const float* gA = x + (size_t)(bt0 + arow) * 512 + aslot * 8;
    int aoff = arow * 64 + ((aslot ^ (arow & 7)) << 3);
    #pragma unroll
    for (int g = 0; g < 8; ++g)
        GLOAD_LDS16(M1bf + (size_t)(w * 64 + g * 8 + lr) * 512 + ((sl ^ lr) << 3),
                    &sB[(w * 64 + g * 8) * 64]);
    {
        float4 f0 = *(const float4*)(gA);
        float4 f1 = *(const float4*)(gA + 4);
        bf16x8 pk;
        pk[0] = (short)f2bf(f0.x); pk[1] = (short)f2bf(f0.y);
        pk[2] = (short)f2bf(f0.z); pk[3] = (short)f2bf(f0.w);
        pk[4] = (short)f2bf(f1.x); pk[5] = (short)f2bf(f1.y);
        pk[6] = (short)f2bf(f1.z); pk[7] = (short)f2bf(f1.w);
        *(bf16x8*)(&sA[aoff]) = pk;
    }
    __syncthreads();
    f32x4 acc[2][8] = {};
    #pragma unroll 1
    for (int rep = 0; rep < 16; ++rep) {
        #pragma unroll 1
        for (int t = 0; t < 8; ++t) {
            #pragma unroll
            for (int kk = 0; kk < 2; ++kk) {
                int slotX = ((kk * 4 + hi) ^ (lo & 7)) << 3;
                bf16x8 a0 = *(const bf16x8*)(&sA[(wm * 32 +      lo) * 64 + slotX]);
                bf16x8 a1 = *(const bf16x8*)(&sA[(wm * 32 + 16 + lo) * 64 + slotX]);
                #pragma unroll
                for (int n = 0; n < 8; ++n) {
                    bf16x8 bb = *(const bf16x8*)(&sB[(wn * 128 + n * 16 + lo) * 64 + slotX]);
                    acc[0][n] = MFMA(a0, bb, acc[0][n]);
                    acc[1][n] = MFMA(a1, bb, acc[1][n]);
                }
            }
        }
    }
    float s = 0.f;
    #pragma unroll
    for (int m = 0; m < 2; ++m)
        #pragma unroll
        for (int n = 0; n < 8; ++n)
            #pragma unroll
            for (int r = 0; r < 4; ++r) s += acc[m][n][r];
    scratch[blockIdx.x * 512 + tid] = s;
}

// PROBE 2: staging-only. 2 reps of the exact staging loop (gload_lds + x loads +
// ds_write + both barriers), no ds_read/MFMA.
__launch_bounds__(512)
__global__ void k_probe_mem(const float* __restrict__ x,
                            const unsigned short* __restrict__ M1bf,
                            float* __restrict__ scratch) {
    __shared__ __align__(16) unsigned short sA[64 * 64];
    __shared__ __align__(16) unsigned short sB[512 * 64];
    int bt0 = blockIdx.x * 64;
    int tid = threadIdx.x, lane = tid & 63, w = tid >> 6;
    int lr = lane >> 3, sl = lane & 7;
    int arow = tid >> 3, aslot = tid & 7;
    const float* gA = x + (size_t)(bt0 + arow) * 512 + aslot * 8;
    int aoff = arow * 64 + ((aslot ^ (arow & 7)) << 3);
    const unsigned short* gB[8];
    #pragma unroll
    for (int g = 0; g < 8; ++g)
        gB[g] = M1bf + (size_t)(w * 64 + g * 8 + lr) * 512 + ((sl ^ lr) << 3);
    #pragma unroll 1
    for (int rep = 0; rep < 2; ++rep) {
        #pragma unroll 1
        for (int k0 = 0; k0 < 512; k0 += 64) {
            if (k0 | rep) __syncthreads();
            #pragma unroll
            for (int g = 0; g < 8; ++g)
                GLOAD_LDS16(gB[g] + k0, &sB[(w * 64 + g * 8) * 64]);
            float4 f0 = *(const float4*)(gA + k0);
            float4 f1 = *(const float4*)(gA + k0 + 4);
            bf16x8 pk;
            pk[0] = (short)f2bf(f0.x); pk[1] = (short)f2bf(f0.y);
            pk[2] = (short)f2bf(f0.z); pk[3] = (short)f2bf(f0.w);
            pk[4] = (short)f2bf(f1.x); pk[5] = (short)f2bf(f1.y);
            pk[6] = (short)f2bf(f1.z); pk[7] = (short)f2bf(f1.w);
            *(bf16x8*)(&sA[aoff]) = pk;
            __syncthreads();
        }
    }
    scratch[blockIdx.x * 512 + tid] = bf2f(sA[tid]) + bf2f(sB[tid]);
}

// PROBE 3: full K-loop (staging + compute), epilogue replaced by acc-sum store. 2 reps.
__launch_bounds__(512)
__global__ void k_probe_noepi(const float* __restrict__ x,
                              const unsigned short* __restrict__ M1bf,
                              float* __restrict__ scratch) {
    __shared__ __align__(16) unsigned short sA[64 * 64];
    __shared__ __align__(16) unsigned short sB[512 * 64];
    int bt0 = blockIdx.x * 64;
    int tid = threadIdx.x, lane = tid & 63, w = tid >> 6;
    int wm = w >> 2, wn = w & 3;
    int lo = lane & 15, hi = lane >> 4;
    int lr = lane >> 3, sl = lane & 7;
    int arow = tid >> 3, aslot = tid & 7;
    const float* gA = x + (size_t)(bt0 + arow) * 512 + aslot * 8;
    int aoff = arow * 64 + ((aslot ^ (arow & 7)) << 3);
    const unsigned short* gB[8];
    #pragma unroll
    for (int g = 0; g < 8; ++g)
        gB[g] = M1bf + (size_t)(w * 64 + g * 8 + lr) * 512 + ((sl ^ lr) << 3);
    f32x4 acc[2][8] = {};
    #pragma unroll 1
    for (int rep = 0; rep < 2; ++rep) {
        #pragma unroll 1
        for (int k0 = 0; k0 < 512; k0 += 64) {
            if (k0 | rep) __syncthreads();
            #pragma unroll
            for (int g = 0; g < 8; ++g)
                GLOAD_LDS16(gB[g] + k0, &sB[(w * 64 + g * 8) * 64]);
            float4 f0 = *(const float4*)(gA + k0);
            float4 f1 = *(const float4*)(gA + k0 + 4);
            bf16x8 pk;
            pk[0] = (short)f2bf(f0.x); pk[1] = (short)f2bf(f0.y);
            pk[2] = (short)f2bf(f0.z); pk[3] = (short)f2bf(f0.w);
            pk[4] = (short)f2bf(f1.x); pk[5] = (short)f2bf(f1.y);
            pk[6] = (short)f2bf(f1.z); pk[7] = (short)f2bf(f1.w);
            *(bf16x8*)(&sA[aoff]) = pk;
            __syncthreads();
            #pragma unroll
            for (int kk = 0; kk < 2; ++kk) {
                int slotX = ((kk * 4 + hi) ^ (lo & 7)) << 3;
                bf16x8 a0 = *(const bf16x8*)(&sA[(wm * 32 +      lo) * 64 + slotX]);
                bf16x8 a1 = *(const bf16x8*)(&sA[(wm * 32 + 16 + lo) * 64 + slotX]);
                #pragma unroll
                for (int n = 0; n < 8; ++n) {
                    bf16x8 bb = *(const bf16x8*)(&sB[(wn * 128 + n * 16 + lo) * 64 + slotX]);
                    acc[0][n] = MFMA(a0, bb, acc[0][n]);
                    acc[1][n] = MFMA(a1, bb, acc[1][n]);
                }
            }
        }
    }
    float s = 0.f;
    #pragma unroll
    for (int m = 0; m < 2; ++m)
        #pragma unroll
        for (int n = 0; n < 8; ++n)
            #pragma unroll
            for (int r = 0; r < 4; ++r) s += acc[m][n][r];
    scratch[blockIdx.x * 512 + tid] = s;
}

// ---------------- GEMM2 + fused LN/tanh/logit (R2 variant — real) ----------------
__launch_bounds__(512)
__global__ void k_gemm2(const float* __restrict__ x,
                        const unsigned short* __restrict__ M1bf,
                        const float* __restrict__ cb,
                        const float* __restrict__ lng, const float* __restrict__ lnb,
                        const float* __restrict__ m2w, const float* __restrict__ m2b,
                        float* __restrict__ logits) {
    __shared__ __align__(16) unsigned short sA[64 * 64];
    __shared__ __align__(16) unsigned short sB[512 * 64];
    __shared__ float sRed[2][8][64];
    __shared__ float sMu[64], sRs[64];
    __shared__ float sLp[8][64];
    int bt0 = blockIdx.x * 64;
    int b = bt0 >> 10;
    int tid = threadIdx.x, lane = tid & 63, w = tid >> 6;
    int wm = w >> 2, wn = w & 3;
    int lo = lane & 15, hi = lane >> 4;
    int lr = lane >> 3, sl = lane & 7;
    int arow = tid >> 3, aslot = tid & 7;
    const float* gA = x + (size_t)(bt0 + arow) * 512 + aslot * 8;
    unsigned short* dAp = sA + arow * 64 + ((aslot ^ (arow & 7)) << 3);
    const unsigned short* gB[8];
    #pragma unroll
    for (int g = 0; g < 8; ++g)
        gB[g] = M1bf + (size_t)(w * 64 + g * 8 + lr) * 512 + ((sl ^ lr) << 3);
    f32x4 acc[2][8] = {};
    for (int k0 = 0; k0 < 512; k0 += 64) {
        if (k0) __syncthreads();
        #pragma unroll
        for (int g = 0; g < 8; ++g)
            GLOAD_LDS16(gB[g] + k0, &sB[(w * 64 + g * 8) * 64]);
        float4 f0 = *(const float4*)(gA + k0);
        float4 f1 = *(const float4*)(gA + k0 + 4);
        bf16x8 pk;
        pk[0] = (short)f2bf(f0.x); pk[1] = (short)f2bf(f0.y);
        pk[2] = (short)f2bf(f0.z); pk[3] = (short)f2bf(f0.w);
        pk[4] = (short)f2bf(f1.x); pk[5] = (short)f2bf(f1.y);
        pk[6] = (short)f2bf(f1.z); pk[7] = (short)f2bf(f1.w);
        *(bf16x8*)dAp = pk;
        __syncthreads();
        #pragma unroll
        for (int kk = 0; kk < 2; ++kk) {
            int slotX = ((kk * 4 + hi) ^ (lo & 7)) << 3;
            bf16x8 a0 = *(const bf16x8*)(sA + (wm * 32 +      lo) * 64 + slotX);
            bf16x8 a1 = *(const bf16x8*)(sA + (wm * 32 + 16 + lo) * 64 + slotX);
            #pragma unroll
            for (int n = 0; n < 8; ++n) {
                bf16x8 bb = *(const bf16x8*)(sB + (wn * 128 + n * 16 + lo) * 64 + slotX);
                acc[0][n] = MFMA(a0, bb, acc[0][n]);
                acc[1][n] = MFMA(a1, bb, acc[1][n]);
            }
        }
    }
    #pragma unroll
    for (int n = 0; n < 8; ++n) {
        float cbv = cb[b * 512 + wn * 128 + n * 16 + lo];
        #pragma unroll
        for (int m = 0; m < 2; ++m)
            #pragma unroll
            for (int r = 0; r < 4; ++r)
                acc[m][n][r] += cbv;
    }
    #pragma unroll
    for (int m = 0; m < 2; ++m) {
        #pragma unroll
        for (int r = 0; r < 4; ++r) {
            float s1 = 0.f, s2 = 0.f;
            #pragma unroll
            for (int n = 0; n < 8; ++n) { float t = acc[m][n][r]; s1 += t; s2 += t * t; }
            #pragma unroll
            for (int msk = 1; msk < 16; msk <<= 1) {
                s1 += __shfl_xor(s1, msk);
                s2 += __shfl_xor(s2, msk);
            }
            if (lo == 0) {
                int row = wm * 32 + m * 16 + hi * 4 + r;
                sRed[0][w][row] = s1;
                sRed[1][w][row] = s2;
            }
        }
    }
    __syncthreads();
    if (tid < 64) {
        int wmr = tid >> 5;
        float s1 = 0.f, s2 = 0.f;
        #pragma unroll
        for (int q = 0; q < 4; ++q) { s1 += sRed[0][wmr * 4 + q][tid]; s2 += sRed[1][wmr * 4 + q][tid]; }
        float mu = s1 * (1.0f / 512.0f);
        float var = s2 * (1.0f / 512.0f) - mu * mu;
        sMu[tid] = mu;
        sRs[tid] = rsqrtf(var + 1e-5f);
    }
    __syncthreads();
    float gv[8], bv[8], wv[8];
    #pragma unroll
    for (int n = 0; n < 8; ++n) {
        int c = wn * 128 + n * 16 + lo;
        gv[n] = lng[c]; bv[n] = lnb[c]; wv[n] = m2w[c];
    }
    #pragma unroll
    for (int m = 0; m < 2; ++m) {
        #pragma unroll
        for (int r = 0; r < 4; ++r) {
            int row = wm * 32 + m * 16 + hi * 4 + r;
            float mu = sMu[row], rs = sRs[row];
            float lg = 0.f;
            #pragma unroll
            for (int n = 0; n < 8; ++n) {
                float h = tanh_fast((acc[m][n][r] - mu) * rs * gv[n] + bv[n]);
                lg += h * wv[n];
            }
            #pragma unroll
            for (int msk = 1; msk < 16; msk <<= 1) lg += __shfl_xor(lg, msk);
            if (lo == 0) sLp[w][row] = lg;
        }
    }
    __syncthreads();
    if (tid < 64) {
        int wmr = tid >> 5;
        float lg = 0.f;
        #pragma unroll
        for (int q = 0; q < 4; ++q) lg += sLp[wmr * 4 + q][tid];
        logits[bt0 + tid] = lg + m2b[0];
    }
}

// ---------------- softmax over T and context ----------------
__global__ void k_softmax(const float* __restrict__ logits, float* __restrict__ wout) {
    int b = blockIdx.x, tid = threadIdx.x;
    __shared__ float red[4];
    float4 v = ((const float4*)(logits + b * 1024))[tid];
    float mx = fmaxf(fmaxf(v.x, v.y), fmaxf(v.z, v.w));
    for (int off = 32; off; off >>= 1) mx = fmaxf(mx, __shfl_xor(mx, off));
    if ((tid & 63) == 0) red[tid >> 6] = mx;
    __syncthreads();
    mx = fmaxf(fmaxf(red[0], red[1]), fmaxf(red[2], red[3]));
    float e0 = expf(v.x - mx), e1 = expf(v.y - mx), e2 = expf(v.z - mx), e3 = expf(v.w - mx);
    float sm = e0 + e1 + e2 + e3;
    for (int off = 32; off; off >>= 1) sm += __shfl_xor(sm, off);
    __syncthreads();
    if ((tid & 63) == 0) red[tid >> 6] = sm;
    __syncthreads();
    float inv = 1.0f / (red[0] + red[1] + red[2] + red[3]);
    float4 o; o.x = e0 * inv; o.y = e1 * inv; o.z = e2 * inv; o.w = e3 * inv;
    ((float4*)(wout + b * 1024))[tid] = o;
}

// context[b][d] = sum_t w[b][t] * x[b][t][d]  (atomic partials; ctx pre-zeroed)
__global__ void k_context(const float* __restrict__ x, const float* __restrict__ wts,
                          float* __restrict__ ctx) {
    int b = blockIdx.x, tc = blockIdx.y;
    int tid = threadIdx.x;
    const float* xp = x + ((size_t)b * 1024 + tc * 64) * 512;
    const float* wp = wts + b * 1024 + tc * 64;
    float a0 = 0.f, a1 = 0.f;
    for (int t = 0; t < 64; ++t) {
        float wv = wp[t];
        a0 += wv * xp[(size_t)t * 512 + tid];
        a1 += wv * xp[(size_t)t * 512 + tid + 256];
    }
    atomicAdd(&ctx[b * 512 + tid], a0);
    atomicAdd(&ctx[b * 512 + tid + 256], a1);
}

// ---------------- launch ----------------
extern "C" void kernel_launch(void* const* d_in, const int* in_sizes, int n_in,
                              void* d_out, int out_size, void* d_ws, size_t ws_size,
                              hipStream_t stream) {
    (void)in_sizes; (void)n_in; (void)out_size; (void)ws_size;
    const float* x    = (const float*)d_in[0];
    const float* Went = (const float*)d_in[1];
    const float* bent = (const float*)d_in[2];
    const float* m1w  = (const float*)d_in[3];
    const float* m1b  = (const float*)d_in[4];
    const float* lng  = (const float*)d_in[5];
    const float* lnb  = (const float*)d_in[6];
    const float* m2w  = (const float*)d_in[7];
    const float* m2b  = (const float*)d_in[8];
    float* out = (float*)d_out;            // [0,8192): context ; [8192,24576): attn
    char* ws = (char*)d_ws;

    unsigned short* Abf   = (unsigned short*)(ws);                        // 4 MB
    unsigned short* WT    = (unsigned short*)(ws + 4194304);              // 8 MB
    float* CpL            = (float*)(ws + 12582912);                      // 8 MB
    float* CpR            = (float*)(ws + 20971520);                      // 8 MB
    unsigned short* M1bf  = (unsigned short*)(ws + 29360128);             // 512 KB
    unsigned short* M2t   = (unsigned short*)(ws + 29884416);             // 512 KB
    float* sumx   = (float*)(ws + 30408704);                              // 32 KB
    float* bias2  = (float*)(ws + 30441472);                              // 2 KB
    float* cb     = (float*)(ws + 30443520);                              // 32 KB
    float* logits = (float*)(ws + 30476288);                              // 64 KB

    hipMemsetAsync(sumx, 0, 512 * 16 * sizeof(float), stream);
    hipMemsetAsync(out, 0, 8192 * sizeof(float), stream);

    k_sumx<<<dim3(16, 16), 256, 0, stream>>>(x, sumx);
    k_prepA<<<512, 256, 0, stream>>>(m1w, bent, Abf, bias2);
    k_conv_W<<<dim3(32, 32), 256, 0, stream>>>(Went, WT);
    k_gemm1<<<dim3(8, 4, 8), 512, 0, stream>>>(Abf, WT, CpL, CpR);
    k_reduce<<<512, 256, 0, stream>>>(CpL, CpR, M1bf, M2t);
    k_cb<<<dim3(16, 8), 256, 0, stream>>>(sumx, M2t, bias2, m1b, cb);

    // diagnostic probes (CpL is dead scratch after k_reduce)
    k_probe_comp <<<256, 512, 0, stream>>>(x, M1bf, CpL);
    k_probe_mem  <<<256, 512, 0, stream>>>(x, M1bf, CpL + 262144);
    k_probe_noepi<<<256, 512, 0, stream>>>(x, M1bf, CpL + 524288);

    k_gemm2<<<256, 512, 0, stream>>>(x, M1bf, cb, lng, lnb, m2w, m2b, logits);
    k_softmax<<<16, 256, 0, stream>>>(logits, out + 8192);
    k_context<<<dim3(16, 16), 256, 0, stream>>>(x, out + 8192, out);
}

// Round 7
// 98.894 us; speedup vs baseline: 2.1559x; 2.1559x over previous
//
#include <hip/hip_runtime.h>
#include <hip/hip_bf16.h>

typedef __attribute__((ext_vector_type(8))) short bf16x8;
typedef __attribute__((ext_vector_type(4))) float f32x4;

__device__ __forceinline__ float bf2f(unsigned short u) {
    union { unsigned int i; float f; } c; c.i = ((unsigned int)u) << 16; return c.f;
}
__device__ __forceinline__ unsigned short f2bf(float f) {
    union { float f; unsigned int i; } c; c.f = f;
    unsigned int x = c.i;
    x += 0x7fffu + ((x >> 16) & 1u);   // round-to-nearest-even
    return (unsigned short)(x >> 16);
}
// pack two f32 -> u32 of 2 bf16 (RNE), elem0 in low half
__device__ __forceinline__ unsigned int pk2(float a, float b) {
    __hip_bfloat162 h = __float22bfloat162_rn(float2{a, b});
    union { __hip_bfloat162 h; unsigned int u; } c; c.h = h; return c.u;
}
__device__ __forceinline__ float tanh_fast(float v) {
    float a = fabsf(v);
    a = fminf(a, 15.0f);
    float e = __expf(2.0f * a);
    float t = 1.0f - 2.0f / (e + 1.0f);
    return copysignf(t, v);
}

// async global->LDS, 16B per lane; lptr must be wave-uniform, gptr per-lane
#define GLOAD_LDS16(gp, lp) \
    __builtin_amdgcn_global_load_lds((const __attribute__((address_space(1))) void*)(gp), \
                                     (__attribute__((address_space(3))) void*)(lp), 16, 0, 0)

#define MFMA(a, b, c) __builtin_amdgcn_mfma_f32_16x16x32_bf16((a), (b), (c), 0, 0, 0)

#define SBAR()  __builtin_amdgcn_s_barrier()
#define SCHED0() __builtin_amdgcn_sched_barrier(0)

// ---------------- small reductions ----------------

// sum over t of x -> sumx[b][d] (atomic partials; sumx pre-zeroed)
__global__ void k_sumx(const float* __restrict__ x, float* __restrict__ sumx) {
    int b = blockIdx.x, tc = blockIdx.y;
    int tid = threadIdx.x;
    const float* xp = x + ((size_t)b * 1024 + tc * 64) * 512;
    float a0 = 0.f, a1 = 0.f;
    for (int t = 0; t < 64; ++t) {
        a0 += xp[(size_t)t * 512 + tid];
        a1 += xp[(size_t)t * 512 + tid + 256];
    }
    atomicAdd(&sumx[b * 512 + tid], a0);
    atomicAdd(&sumx[b * 512 + tid + 256], a1);
}

// Abf[i][k] = bf16(m1w[i][k]) (natural order; K index k = e*8+s), fused with
// bias2[i] = sum_k m1w[i,k] * b_ent[(k&7)*512 + (k>>3)]
__global__ void k_prepA(const float* __restrict__ m1w, const float* __restrict__ bent,
                        unsigned short* __restrict__ Abf, float* __restrict__ bias2) {
    int i = blockIdx.x, tid = threadIdx.x;
    const float* row = m1w + (size_t)i * 4096;
    float acc = 0.f;
    #pragma unroll
    for (int q = 0; q < 4; ++q) {
        int col = q * 1024 + tid * 4;
        float4 v = *(const float4*)(row + col);
        ushort4 o;
        o.x = f2bf(v.x); o.y = f2bf(v.y); o.z = f2bf(v.z); o.w = f2bf(v.w);
        *(ushort4*)(Abf + (size_t)i * 4096 + col) = o;
        int e0 = col >> 3, s0 = col & 7;
        acc += v.x * bent[(s0    ) * 512 + e0];
        acc += v.y * bent[(s0 + 1) * 512 + e0];
        acc += v.z * bent[(s0 + 2) * 512 + e0];
        acc += v.w * bent[(s0 + 3) * 512 + e0];
    }
    #pragma unroll
    for (int off = 32; off; off >>= 1) acc += __shfl_xor(acc, off);
    __shared__ float r4[4];
    if ((tid & 63) == 0) r4[tid >> 6] = acc;
    __syncthreads();
    if (tid == 0) bias2[i] = r4[0] + r4[1] + r4[2] + r4[3];
}

// WT[j][k] = bf16(W_ent[(k&7)*512 + (k>>3)][j]); k = e*8+s
__global__ void k_conv_W(const float* __restrict__ W, unsigned short* __restrict__ WT) {
    __shared__ float tile[128][33];
    int e0 = blockIdx.x * 16;
    int j0 = blockIdx.y * 32;
    int tid = threadIdx.x;
    int tx = tid & 31, ty = tid >> 5;
    #pragma unroll
    for (int q = 0; q < 16; ++q) {
        int lk = q * 8 + ty;
        int de = lk >> 3, s = lk & 7;
        int r = s * 512 + e0 + de;
        tile[lk][tx] = W[(size_t)r * 1024 + j0 + tx];
    }
    __syncthreads();
    int j = tid >> 3, ck = (tid & 7) * 16;
    unsigned short* dst = WT + (size_t)(j0 + j) * 4096 + e0 * 8 + ck;
    #pragma unroll
    for (int g = 0; g < 4; ++g) {
        ushort4 o;
        o.x = f2bf(tile[ck + g * 4 + 0][j]);
        o.y = f2bf(tile[ck + g * 4 + 1][j]);
        o.z = f2bf(tile[ck + g * 4 + 2][j]);
        o.w = f2bf(tile[ck + g * 4 + 3][j]);
        *(ushort4*)(dst + g * 4) = o;
    }
}

// ---------------- GEMM1 (split-K=8, pipelined): C[i,j] = sum_k Abf[i,k] WT[j,k] ----------------
__launch_bounds__(512, 2)
__global__ void k_gemm1(const unsigned short* __restrict__ Abf,
                        const unsigned short* __restrict__ WT,
                        float* __restrict__ CpL, float* __restrict__ CpR) {
    __shared__ __align__(16) unsigned short sA[2][64 * 64];
    __shared__ __align__(16) unsigned short sB[2][256 * 64];
    int i0 = blockIdx.x * 64;
    int j0 = blockIdx.y * 256;
    int kbase = blockIdx.z * 512;
    int tid = threadIdx.x, lane = tid & 63, w = tid >> 6;
    int wm = w >> 2, wn = w & 3;
    int lr = lane >> 3, sl = lane & 7;
    int lo = lane & 15, hi = lane >> 4;
    int arow = w * 8 + lr;
    const unsigned short* gA = Abf + (size_t)(i0 + arow) * 4096 + kbase + ((sl ^ lr) << 3);
    const unsigned short* gB0 = WT + (size_t)(j0 + w * 32 + 0 * 8 + lr) * 4096 + kbase + ((sl ^ lr) << 3);
    const unsigned short* gB1 = WT + (size_t)(j0 + w * 32 + 1 * 8 + lr) * 4096 + kbase + ((sl ^ lr) << 3);
    const unsigned short* gB2 = WT + (size_t)(j0 + w * 32 + 2 * 8 + lr) * 4096 + kbase + ((sl ^ lr) << 3);
    const unsigned short* gB3 = WT + (size_t)(j0 + w * 32 + 3 * 8 + lr) * 4096 + kbase + ((sl ^ lr) << 3);
    bool left = (blockIdx.y < 2);
    f32x4 acc[2][4] = {};

#define G1_STAGE(tt, bufn)                                                    \
    do {                                                                      \
        int koff = (tt) * 64;                                                 \
        GLOAD_LDS16(gA + koff, &sA[bufn][w * 8 * 64]);                        \
        GLOAD_LDS16(gB0 + koff, &sB[bufn][(w * 32 + 0) * 64]);                \
        GLOAD_LDS16(gB1 + koff, &sB[bufn][(w * 32 + 8) * 64]);                \
        GLOAD_LDS16(gB2 + koff, &sB[bufn][(w * 32 + 16) * 64]);               \
        GLOAD_LDS16(gB3 + koff, &sB[bufn][(w * 32 + 24) * 64]);               \
        SCHED0();                                                             \
    } while (0)

    G1_STAGE(0, 0);
    #pragma unroll
    for (int t = 0; t < 8; ++t) {
        int buf = t & 1;
        if (t < 7) {
            G1_STAGE(t + 1, buf ^ 1);
            asm volatile("s_waitcnt vmcnt(5)" ::: "memory");
        } else {
            asm volatile("s_waitcnt vmcnt(0)" ::: "memory");
        }
        SCHED0(); SBAR(); SCHED0();
        __builtin_amdgcn_s_setprio(1);
        #pragma unroll
        for (int kk = 0; kk < 2; ++kk) {
            int slotX = ((kk * 4 + hi) ^ (lo & 7)) << 3;
            bf16x8 a0 = *(const bf16x8*)(&sA[buf][(wm * 32 +      lo) * 64 + slotX]);
            bf16x8 a1 = *(const bf16x8*)(&sA[buf][(wm * 32 + 16 + lo) * 64 + slotX]);
            #pragma unroll
            for (int n = 0; n < 4; ++n) {
                bf16x8 bb = *(const bf16x8*)(&sB[buf][(wn * 64 + n * 16 + lo) * 64 + slotX]);
                if (left) {
                    acc[0][n] = MFMA(a0, bb, acc[0][n]);
                    acc[1][n] = MFMA(a1, bb, acc[1][n]);
                } else {
                    acc[0][n] = MFMA(bb, a0, acc[0][n]);
                    acc[1][n] = MFMA(bb, a1, acc[1][n]);
                }
            }
        }
        __builtin_amdgcn_s_setprio(0);
        if (t < 7) { SCHED0(); SBAR(); SCHED0(); }
    }
#undef G1_STAGE

    int ksoff = blockIdx.z * 262144;
    if (left) {
        #pragma unroll
        for (int m = 0; m < 2; ++m) {
            int ib = i0 + wm * 32 + m * 16 + hi * 4;
            #pragma unroll
            for (int n = 0; n < 4; ++n) {
                int j = j0 + wn * 64 + n * 16 + lo;
                #pragma unroll
                for (int r = 0; r < 4; ++r)
                    CpL[ksoff + (ib + r) * 512 + j] = acc[m][n][r];
            }
        }
    } else {
        #pragma unroll
        for (int m = 0; m < 2; ++m) {
            int ic = i0 + wm * 32 + m * 16 + lo;
            #pragma unroll
            for (int n = 0; n < 4; ++n) {
                int db = j0 - 512 + wn * 64 + n * 16 + hi * 4;
                #pragma unroll
                for (int r = 0; r < 4; ++r)
                    CpR[ksoff + (db + r) * 512 + ic] = acc[m][n][r];
            }
        }
    }
}

// sum 8 split-K partials -> bf16; blocks 0..255 -> M1bf (row-major), 256..511 -> M2t
__global__ void k_reduce(const float* __restrict__ CpL, const float* __restrict__ CpR,
                         unsigned short* __restrict__ M1bf, unsigned short* __restrict__ M2t) {
    int bx = blockIdx.x;
    const float* Cp = (bx < 256) ? CpL : CpR;
    unsigned short* ob = (bx < 256) ? M1bf : M2t;
    int gid = (bx & 255) * 256 + threadIdx.x;
    float4 s = ((const float4*)Cp)[gid];
    #pragma unroll
    for (int ks = 1; ks < 8; ++ks) {
        float4 t = ((const float4*)Cp)[ks * 65536 + gid];
        s.x += t.x; s.y += t.y; s.z += t.z; s.w += t.w;
    }
    ushort4 o;
    o.x = f2bf(s.x); o.y = f2bf(s.y); o.z = f2bf(s.z); o.w = f2bf(s.w);
    ((ushort4*)ob)[gid] = o;
}

// cb[b][i] = (1/T) * sum_d sumx[b][d]*M2t[d][i] + bias2[i] + m1b[i]
__global__ void k_cb(const float* __restrict__ sumx, const unsigned short* __restrict__ M2t,
                     const float* __restrict__ bias2, const float* __restrict__ m1b,
                     float* __restrict__ cbo) {
    int b = blockIdx.x, i0 = blockIdx.y * 64;
    int tid = threadIdx.x;
    int il = tid & 63, dq = tid >> 6;
    const float* sx = sumx + b * 512 + dq * 128;
    const unsigned short* mp = M2t + (size_t)dq * 128 * 512 + i0 + il;
    float acc = 0.f;
    #pragma unroll 4
    for (int dd = 0; dd < 128; ++dd)
        acc += sx[dd] * bf2f(mp[(size_t)dd * 512]);
    __shared__ float sPart[4][64];
    sPart[dq][il] = acc;
    __syncthreads();
    if (tid < 64) {
        float v = sPart[0][tid] + sPart[1][tid] + sPart[2][tid] + sPart[3][tid];
        cbo[b * 512 + i0 + tid] = v * (1.0f / 1024.0f) + bias2[i0 + tid] + m1b[i0 + tid];
    }
}

// ---------------- GEMM2 (K-loop only) -> fragment-packed bf16 y ----------------
// y[bt,i] = sum_d x[bt,d]*M1[i,d]  (cb added later in k_lnlogit)
// Output layout: per 64-row block: chunk c = w*16 + m*8 + n (256 elems), elem
// (hi*16+lo)*4 + r  ==> value for row bt0+wm*32+m*16+hi*4+r, col wn*128+n*16+lo.
__launch_bounds__(512)
__global__ void k_gemm2s(const float* __restrict__ x,
                         const unsigned short* __restrict__ M1bf,
                         unsigned short* __restrict__ ypk) {
    __shared__ __align__(16) unsigned short sA[64 * 64];
    __shared__ __align__(16) unsigned short sB[512 * 64];
    int bt0 = blockIdx.x * 64;
    int tid = threadIdx.x, lane = tid & 63, w = tid >> 6;
    int wm = w >> 2, wn = w & 3;
    int lo = lane & 15, hi = lane >> 4;
    int lr = lane >> 3, sl = lane & 7;
    int arow = tid >> 3, aslot = tid & 7;
    const float* gA = x + (size_t)(bt0 + arow) * 512 + aslot * 8;
    unsigned short* dAp = sA + arow * 64 + ((aslot ^ (arow & 7)) << 3);
    const unsigned short* gB[8];
    #pragma unroll
    for (int g = 0; g < 8; ++g)
        gB[g] = M1bf + (size_t)(w * 64 + g * 8 + lr) * 512 + ((sl ^ lr) << 3);
    f32x4 acc[2][8] = {};
    for (int k0 = 0; k0 < 512; k0 += 64) {
        if (k0) __syncthreads();
        #pragma unroll
        for (int g = 0; g < 8; ++g)
            GLOAD_LDS16(gB[g] + k0, &sB[(w * 64 + g * 8) * 64]);
        float4 f0 = *(const float4*)(gA + k0);
        float4 f1 = *(const float4*)(gA + k0 + 4);
        bf16x8 pk;
        pk[0] = (short)f2bf(f0.x); pk[1] = (short)f2bf(f0.y);
        pk[2] = (short)f2bf(f0.z); pk[3] = (short)f2bf(f0.w);
        pk[4] = (short)f2bf(f1.x); pk[5] = (short)f2bf(f1.y);
        pk[6] = (short)f2bf(f1.z); pk[7] = (short)f2bf(f1.w);
        *(bf16x8*)dAp = pk;
        __syncthreads();
        #pragma unroll
        for (int kk = 0; kk < 2; ++kk) {
            int slotX = ((kk * 4 + hi) ^ (lo & 7)) << 3;
            bf16x8 a0 = *(const bf16x8*)(sA + (wm * 32 +      lo) * 64 + slotX);
            bf16x8 a1 = *(const bf16x8*)(sA + (wm * 32 + 16 + lo) * 64 + slotX);
            #pragma unroll
            for (int n = 0; n < 8; ++n) {
                bf16x8 bb = *(const bf16x8*)(sB + (wn * 128 + n * 16 + lo) * 64 + slotX);
                acc[0][n] = MFMA(a0, bb, acc[0][n]);
                acc[1][n] = MFMA(a1, bb, acc[1][n]);
            }
        }
    }
    // store fragment-packed bf16: fully coalesced 8B/lane per (m,n)
    unsigned short* yb = ypk + (size_t)blockIdx.x * 32768;
    #pragma unroll
    for (int m = 0; m < 2; ++m) {
        #pragma unroll
        for (int n = 0; n < 8; ++n) {
            unsigned int u0 = pk2(acc[m][n][0], acc[m][n][1]);
            unsigned int u1 = pk2(acc[m][n][2], acc[m][n][3]);
            uint2 o; o.x = u0; o.y = u1;
            *(uint2*)(yb + (((w * 16 + m * 8 + n) << 8) + (lane << 2))) = o;
        }
    }
}

// ---------------- LN + tanh + logit (reads fragment-packed y) ----------------
__launch_bounds__(512)
__global__ void k_lnlogit(const unsigned short* __restrict__ ypk,
                          const float* __restrict__ cb,
                          const float* __restrict__ lng, const float* __restrict__ lnb,
                          const float* __restrict__ m2w, const float* __restrict__ m2b,
                          float* __restrict__ logits) {
    __shared__ __align__(16) unsigned short sY[32768];   // 64 KB
    __shared__ float sCb[512], sG[512], sBe[512], sW[512];
    __shared__ float sS1[64][8], sS2[64][8], sLg[64][8];
    int blk = blockIdx.x;
    int bt0 = blk * 64;
    int b = bt0 >> 10;
    int tid = threadIdx.x, w = tid >> 6, lane = tid & 63;
    sCb[tid] = cb[b * 512 + tid];
    sG[tid]  = lng[tid];
    sBe[tid] = lnb[tid];
    sW[tid]  = m2w[tid];
    const unsigned short* src = ypk + (size_t)blk * 32768;
    #pragma unroll
    for (int it = 0; it < 8; ++it) {
        int off = (w * 8 + it) * 512;           // ushorts; wave-linear 1KB chunks
        GLOAD_LDS16(src + off + (lane << 3), &sY[off]);   // per-lane source (fix)
    }
    asm volatile("s_waitcnt vmcnt(0)" ::: "memory");
    __syncthreads();

    int row = tid >> 3, sub = tid & 7;
    int wm = row >> 5, m = (row >> 4) & 1, hi = (row >> 2) & 3, r = row & 3;
    float s1 = 0.f, s2 = 0.f;
    #pragma unroll
    for (int wn = 0; wn < 4; ++wn) {
        #pragma unroll
        for (int n = 0; n < 8; ++n) {
            int c = (wm * 4 + wn) * 16 + m * 8 + n;
            int eb = c * 256 + r;
            int ib = wn * 128 + n * 16;
            #pragma unroll
            for (int l2 = 0; l2 < 2; ++l2) {
                int lo = sub * 2 + l2;
                float v = bf2f(sY[eb + (hi * 16 + lo) * 4]) + sCb[ib + lo];
                s1 += v; s2 += v * v;
            }
        }
    }
    sS1[row][sub] = s1; sS2[row][sub] = s2;
    __syncthreads();
    float a1 = 0.f, a2 = 0.f;
    #pragma unroll
    for (int q = 0; q < 8; ++q) { a1 += sS1[row][q]; a2 += sS2[row][q]; }
    float mu = a1 * (1.0f / 512.0f);
    float var = a2 * (1.0f / 512.0f) - mu * mu;
    float rs = rsqrtf(var + 1e-5f);
    float lg = 0.f;
    #pragma unroll
    for (int wn = 0; wn < 4; ++wn) {
        #pragma unroll
        for (int n = 0; n < 8; ++n) {
            int c = (wm * 4 + wn) * 16 + m * 8 + n;
            int eb = c * 256 + r;
            int ib = wn * 128 + n * 16;
            #pragma unroll
            for (int l2 = 0; l2 < 2; ++l2) {
                int lo = sub * 2 + l2;
                float v = bf2f(sY[eb + (hi * 16 + lo) * 4]) + sCb[ib + lo];
                float h = tanh_fast((v - mu) * rs * sG[ib + lo] + sBe[ib + lo]);
                lg += h * sW[ib + lo];
            }
        }
    }
    sLg[row][sub] = lg;
    __syncthreads();
    if (sub == 0) {
        float t = 0.f;
        #pragma unroll
        for (int q = 0; q < 8; ++q) t += sLg[row][q];
        logits[bt0 + row] = t + m2b[0];
    }
}

// ---------------- softmax over T and context ----------------
__global__ void k_softmax(const float* __restrict__ logits, float* __restrict__ wout) {
    int b = blockIdx.x, tid = threadIdx.x;
    __shared__ float red[4];
    float4 v = ((const float4*)(logits + b * 1024))[tid];
    float mx = fmaxf(fmaxf(v.x, v.y), fmaxf(v.z, v.w));
    for (int off = 32; off; off >>= 1) mx = fmaxf(mx, __shfl_xor(mx, off));
    if ((tid & 63) == 0) red[tid >> 6] = mx;
    __syncthreads();
    mx = fmaxf(fmaxf(red[0], red[1]), fmaxf(red[2], red[3]));
    float e0 = expf(v.x - mx), e1 = expf(v.y - mx), e2 = expf(v.z - mx), e3 = expf(v.w - mx);
    float sm = e0 + e1 + e2 + e3;
    for (int off = 32; off; off >>= 1) sm += __shfl_xor(sm, off);
    __syncthreads();
    if ((tid & 63) == 0) red[tid >> 6] = sm;
    __syncthreads();
    float inv = 1.0f / (red[0] + red[1] + red[2] + red[3]);
    float4 o; o.x = e0 * inv; o.y = e1 * inv; o.z = e2 * inv; o.w = e3 * inv;
    ((float4*)(wout + b * 1024))[tid] = o;
}

// context[b][d] = sum_t w[b][t] * x[b][t][d]  (atomic partials; ctx pre-zeroed)
__global__ void k_context(const float* __restrict__ x, const float* __restrict__ wts,
                          float* __restrict__ ctx) {
    int b = blockIdx.x, tc = blockIdx.y;
    int tid = threadIdx.x;
    const float* xp = x + ((size_t)b * 1024 + tc * 64) * 512;
    const float* wp = wts + b * 1024 + tc * 64;
    float a0 = 0.f, a1 = 0.f;
    for (int t = 0; t < 64; ++t) {
        float wv = wp[t];
        a0 += wv * xp[(size_t)t * 512 + tid];
        a1 += wv * xp[(size_t)t * 512 + tid + 256];
    }
    atomicAdd(&ctx[b * 512 + tid], a0);
    atomicAdd(&ctx[b * 512 + tid + 256], a1);
}

// ---------------- launch ----------------
extern "C" void kernel_launch(void* const* d_in, const int* in_sizes, int n_in,
                              void* d_out, int out_size, void* d_ws, size_t ws_size,
                              hipStream_t stream) {
    (void)in_sizes; (void)n_in; (void)out_size; (void)ws_size;
    const float* x    = (const float*)d_in[0];
    const float* Went = (const float*)d_in[1];
    const float* bent = (const float*)d_in[2];
    const float* m1w  = (const float*)d_in[3];
    const float* m1b  = (const float*)d_in[4];
    const float* lng  = (const float*)d_in[5];
    const float* lnb  = (const float*)d_in[6];
    const float* m2w  = (const float*)d_in[7];
    const float* m2b  = (const float*)d_in[8];
    float* out = (float*)d_out;            // [0,8192): context ; [8192,24576): attn
    char* ws = (char*)d_ws;

    unsigned short* Abf   = (unsigned short*)(ws);                        // 4 MB
    unsigned short* WT    = (unsigned short*)(ws + 4194304);              // 8 MB
    float* CpL            = (float*)(ws + 12582912);                      // 8 MB
    float* CpR            = (float*)(ws + 20971520);                      // 8 MB
    unsigned short* ypk   = (unsigned short*)(ws + 12582912);             // 16 MB (reuses CpL/CpR after k_reduce)
    unsigned short* M1bf  = (unsigned short*)(ws + 29360128);             // 512 KB
    unsigned short* M2t   = (unsigned short*)(ws + 29884416);             // 512 KB
    float* sumx   = (float*)(ws + 30408704);                              // 32 KB
    float* bias2  = (float*)(ws + 30441472);                              // 2 KB
    float* cb     = (float*)(ws + 30443520);                              // 32 KB
    float* logits = (float*)(ws + 30476288);                              // 64 KB

    hipMemsetAsync(sumx, 0, 512 * 16 * sizeof(float), stream);
    hipMemsetAsync(out, 0, 8192 * sizeof(float), stream);

    k_sumx<<<dim3(16, 16), 256, 0, stream>>>(x, sumx);
    k_prepA<<<512, 256, 0, stream>>>(m1w, bent, Abf, bias2);
    k_conv_W<<<dim3(32, 32), 256, 0, stream>>>(Went, WT);
    k_gemm1<<<dim3(8, 4, 8), 512, 0, stream>>>(Abf, WT, CpL, CpR);
    k_reduce<<<512, 256, 0, stream>>>(CpL, CpR, M1bf, M2t);
    k_cb<<<dim3(16, 8), 256, 0, stream>>>(sumx, M2t, bias2, m1b, cb);
    k_gemm2s<<<256, 512, 0, stream>>>(x, M1bf, ypk);
    k_lnlogit<<<256, 512, 0, stream>>>(ypk, cb, lng, lnb, m2w, m2b, logits);
    k_softmax<<<16, 256, 0, stream>>>(logits, out + 8192);
    k_context<<<dim3(16, 16), 256, 0, stream>>>(x, out + 8192, out);
}

// Round 8
// 86.055 us; speedup vs baseline: 2.4776x; 1.1492x over previous
//
#include <hip/hip_runtime.h>
#include <hip/hip_bf16.h>

typedef __attribute__((ext_vector_type(8))) short bf16x8;
typedef __attribute__((ext_vector_type(4))) float f32x4;

__device__ __forceinline__ float bf2f(unsigned short u) {
    union { unsigned int i; float f; } c; c.i = ((unsigned int)u) << 16; return c.f;
}
__device__ __forceinline__ unsigned short f2bf(float f) {
    union { float f; unsigned int i; } c; c.f = f;
    unsigned int x = c.i;
    x += 0x7fffu + ((x >> 16) & 1u);   // round-to-nearest-even
    return (unsigned short)(x >> 16);
}
// pack two f32 -> u32 of 2 bf16 (RNE), elem0 in low half
__device__ __forceinline__ unsigned int pk2(float a, float b) {
    __hip_bfloat162 h = __float22bfloat162_rn(float2{a, b});
    union { __hip_bfloat162 h; unsigned int u; } c; c.h = h; return c.u;
}
__device__ __forceinline__ float tanh_fast(float v) {
    float a = fabsf(v);
    a = fminf(a, 15.0f);
    float e = __expf(2.0f * a);
    float t = 1.0f - 2.0f / (e + 1.0f);
    return copysignf(t, v);
}

// async global->LDS, 16B per lane; lptr must be wave-uniform, gptr per-lane
#define GLOAD_LDS16(gp, lp) \
    __builtin_amdgcn_global_load_lds((const __attribute__((address_space(1))) void*)(gp), \
                                     (__attribute__((address_space(3))) void*)(lp), 16, 0, 0)

#define MFMA(a, b, c) __builtin_amdgcn_mfma_f32_16x16x32_bf16((a), (b), (c), 0, 0, 0)

#define SBAR()  __builtin_amdgcn_s_barrier()
#define SCHED0() __builtin_amdgcn_sched_barrier(0)

// ---------------- partial reductions (no atomics, no memset) ----------------

// per-(b,tc) partial sum over 64 t's -> sumxp[(b*16+tc)*512 + d]
__global__ void k_sumxp(const float* __restrict__ x, float* __restrict__ sumxp) {
    int b = blockIdx.x, tc = blockIdx.y;
    int tid = threadIdx.x;
    const float* xp = x + ((size_t)b * 1024 + tc * 64) * 512;
    float a0 = 0.f, a1 = 0.f;
    for (int t = 0; t < 64; ++t) {
        a0 += xp[(size_t)t * 512 + tid];
        a1 += xp[(size_t)t * 512 + tid + 256];
    }
    float* o = sumxp + (size_t)(b * 16 + tc) * 512;
    o[tid] = a0;
    o[tid + 256] = a1;
}

// Abf[i][k] = bf16(m1w[i][k]) (natural order; K index k = e*8+s), fused with
// bias2[i] = sum_k m1w[i,k] * b_ent[(k&7)*512 + (k>>3)]
__global__ void k_prepA(const float* __restrict__ m1w, const float* __restrict__ bent,
                        unsigned short* __restrict__ Abf, float* __restrict__ bias2) {
    int i = blockIdx.x, tid = threadIdx.x;
    const float* row = m1w + (size_t)i * 4096;
    float acc = 0.f;
    #pragma unroll
    for (int q = 0; q < 4; ++q) {
        int col = q * 1024 + tid * 4;
        float4 v = *(const float4*)(row + col);
        ushort4 o;
        o.x = f2bf(v.x); o.y = f2bf(v.y); o.z = f2bf(v.z); o.w = f2bf(v.w);
        *(ushort4*)(Abf + (size_t)i * 4096 + col) = o;
        int e0 = col >> 3, s0 = col & 7;
        acc += v.x * bent[(s0    ) * 512 + e0];
        acc += v.y * bent[(s0 + 1) * 512 + e0];
        acc += v.z * bent[(s0 + 2) * 512 + e0];
        acc += v.w * bent[(s0 + 3) * 512 + e0];
    }
    #pragma unroll
    for (int off = 32; off; off >>= 1) acc += __shfl_xor(acc, off);
    __shared__ float r4[4];
    if ((tid & 63) == 0) r4[tid >> 6] = acc;
    __syncthreads();
    if (tid == 0) bias2[i] = r4[0] + r4[1] + r4[2] + r4[3];
}

// WT[j][k] = bf16(W_ent[(k&7)*512 + (k>>3)][j]); k = e*8+s
__global__ void k_conv_W(const float* __restrict__ W, unsigned short* __restrict__ WT) {
    __shared__ float tile[128][33];
    int e0 = blockIdx.x * 16;
    int j0 = blockIdx.y * 32;
    int tid = threadIdx.x;
    int tx = tid & 31, ty = tid >> 5;
    #pragma unroll
    for (int q = 0; q < 16; ++q) {
        int lk = q * 8 + ty;
        int de = lk >> 3, s = lk & 7;
        int r = s * 512 + e0 + de;
        tile[lk][tx] = W[(size_t)r * 1024 + j0 + tx];
    }
    __syncthreads();
    int j = tid >> 3, ck = (tid & 7) * 16;
    unsigned short* dst = WT + (size_t)(j0 + j) * 4096 + e0 * 8 + ck;
    #pragma unroll
    for (int g = 0; g < 4; ++g) {
        ushort4 o;
        o.x = f2bf(tile[ck + g * 4 + 0][j]);
        o.y = f2bf(tile[ck + g * 4 + 1][j]);
        o.z = f2bf(tile[ck + g * 4 + 2][j]);
        o.w = f2bf(tile[ck + g * 4 + 3][j]);
        *(ushort4*)(dst + g * 4) = o;
    }
}

// ---------------- GEMM1 (split-K=8, pipelined): C[i,j] = sum_k Abf[i,k] WT[j,k] ----------------
__launch_bounds__(512, 2)
__global__ void k_gemm1(const unsigned short* __restrict__ Abf,
                        const unsigned short* __restrict__ WT,
                        float* __restrict__ CpL, float* __restrict__ CpR) {
    __shared__ __align__(16) unsigned short sA[2][64 * 64];
    __shared__ __align__(16) unsigned short sB[2][256 * 64];
    int i0 = blockIdx.x * 64;
    int j0 = blockIdx.y * 256;
    int kbase = blockIdx.z * 512;
    int tid = threadIdx.x, lane = tid & 63, w = tid >> 6;
    int wm = w >> 2, wn = w & 3;
    int lr = lane >> 3, sl = lane & 7;
    int lo = lane & 15, hi = lane >> 4;
    int arow = w * 8 + lr;
    const unsigned short* gA = Abf + (size_t)(i0 + arow) * 4096 + kbase + ((sl ^ lr) << 3);
    const unsigned short* gB0 = WT + (size_t)(j0 + w * 32 + 0 * 8 + lr) * 4096 + kbase + ((sl ^ lr) << 3);
    const unsigned short* gB1 = WT + (size_t)(j0 + w * 32 + 1 * 8 + lr) * 4096 + kbase + ((sl ^ lr) << 3);
    const unsigned short* gB2 = WT + (size_t)(j0 + w * 32 + 2 * 8 + lr) * 4096 + kbase + ((sl ^ lr) << 3);
    const unsigned short* gB3 = WT + (size_t)(j0 + w * 32 + 3 * 8 + lr) * 4096 + kbase + ((sl ^ lr) << 3);
    bool left = (blockIdx.y < 2);
    f32x4 acc[2][4] = {};

#define G1_STAGE(tt, bufn)                                                    \
    do {                                                                      \
        int koff = (tt) * 64;                                                 \
        GLOAD_LDS16(gA + koff, &sA[bufn][w * 8 * 64]);                        \
        GLOAD_LDS16(gB0 + koff, &sB[bufn][(w * 32 + 0) * 64]);                \
        GLOAD_LDS16(gB1 + koff, &sB[bufn][(w * 32 + 8) * 64]);                \
        GLOAD_LDS16(gB2 + koff, &sB[bufn][(w * 32 + 16) * 64]);               \
        GLOAD_LDS16(gB3 + koff, &sB[bufn][(w * 32 + 24) * 64]);               \
        SCHED0();                                                             \
    } while (0)

    G1_STAGE(0, 0);
    #pragma unroll
    for (int t = 0; t < 8; ++t) {
        int buf = t & 1;
        if (t < 7) {
            G1_STAGE(t + 1, buf ^ 1);
            asm volatile("s_waitcnt vmcnt(5)" ::: "memory");
        } else {
            asm volatile("s_waitcnt vmcnt(0)" ::: "memory");
        }
        SCHED0(); SBAR(); SCHED0();
        __builtin_amdgcn_s_setprio(1);
        #pragma unroll
        for (int kk = 0; kk < 2; ++kk) {
            int slotX = ((kk * 4 + hi) ^ (lo & 7)) << 3;
            bf16x8 a0 = *(const bf16x8*)(&sA[buf][(wm * 32 +      lo) * 64 + slotX]);
            bf16x8 a1 = *(const bf16x8*)(&sA[buf][(wm * 32 + 16 + lo) * 64 + slotX]);
            #pragma unroll
            for (int n = 0; n < 4; ++n) {
                bf16x8 bb = *(const bf16x8*)(&sB[buf][(wn * 64 + n * 16 + lo) * 64 + slotX]);
                if (left) {
                    acc[0][n] = MFMA(a0, bb, acc[0][n]);
                    acc[1][n] = MFMA(a1, bb, acc[1][n]);
                } else {
                    acc[0][n] = MFMA(bb, a0, acc[0][n]);
                    acc[1][n] = MFMA(bb, a1, acc[1][n]);
                }
            }
        }
        __builtin_amdgcn_s_setprio(0);
        if (t < 7) { SCHED0(); SBAR(); SCHED0(); }
    }
#undef G1_STAGE

    int ksoff = blockIdx.z * 262144;
    if (left) {
        #pragma unroll
        for (int m = 0; m < 2; ++m) {
            int ib = i0 + wm * 32 + m * 16 + hi * 4;
            #pragma unroll
            for (int n = 0; n < 4; ++n) {
                int j = j0 + wn * 64 + n * 16 + lo;
                #pragma unroll
                for (int r = 0; r < 4; ++r)
                    CpL[ksoff + (ib + r) * 512 + j] = acc[m][n][r];
            }
        }
    } else {
        #pragma unroll
        for (int m = 0; m < 2; ++m) {
            int ic = i0 + wm * 32 + m * 16 + lo;
            #pragma unroll
            for (int n = 0; n < 4; ++n) {
                int db = j0 - 512 + wn * 64 + n * 16 + hi * 4;
                #pragma unroll
                for (int r = 0; r < 4; ++r)
                    CpR[ksoff + (db + r) * 512 + ic] = acc[m][n][r];
            }
        }
    }
}

// sum 8 split-K partials -> bf16; blocks 0..255 -> M1bf (row-major), 256..511 -> M2t
__global__ void k_reduce(const float* __restrict__ CpL, const float* __restrict__ CpR,
                         unsigned short* __restrict__ M1bf, unsigned short* __restrict__ M2t) {
    int bx = blockIdx.x;
    const float* Cp = (bx < 256) ? CpL : CpR;
    unsigned short* ob = (bx < 256) ? M1bf : M2t;
    int gid = (bx & 255) * 256 + threadIdx.x;
    float4 s = ((const float4*)Cp)[gid];
    #pragma unroll
    for (int ks = 1; ks < 8; ++ks) {
        float4 t = ((const float4*)Cp)[ks * 65536 + gid];
        s.x += t.x; s.y += t.y; s.z += t.z; s.w += t.w;
    }
    ushort4 o;
    o.x = f2bf(s.x); o.y = f2bf(s.y); o.z = f2bf(s.z); o.w = f2bf(s.w);
    ((ushort4*)ob)[gid] = o;
}

// cb[b][i] = (1/T) * sum_d sumx[b][d]*M2t[d][i] + bias2[i] + m1b[i]
// sumx reduced in-block from 16 partials
__global__ void k_cb(const float* __restrict__ sumxp, const unsigned short* __restrict__ M2t,
                     const float* __restrict__ bias2, const float* __restrict__ m1b,
                     float* __restrict__ cbo) {
    int b = blockIdx.x, i0 = blockIdx.y * 64;
    int tid = threadIdx.x;
    __shared__ float sSx[512];
    for (int d = tid; d < 512; d += 256) {
        float s = 0.f;
        #pragma unroll
        for (int p = 0; p < 16; ++p)
            s += sumxp[(size_t)(b * 16 + p) * 512 + d];
        sSx[d] = s;
    }
    __syncthreads();
    int il = tid & 63, dq = tid >> 6;
    const unsigned short* mp = M2t + (size_t)dq * 128 * 512 + i0 + il;
    float acc = 0.f;
    #pragma unroll 4
    for (int dd = 0; dd < 128; ++dd)
        acc += sSx[dq * 128 + dd] * bf2f(mp[(size_t)dd * 512]);
    __shared__ float sPart[4][64];
    sPart[dq][il] = acc;
    __syncthreads();
    if (tid < 64) {
        float v = sPart[0][tid] + sPart[1][tid] + sPart[2][tid] + sPart[3][tid];
        cbo[b * 512 + i0 + tid] = v * (1.0f / 1024.0f) + bias2[i0 + tid] + m1b[i0 + tid];
    }
}

// ---------------- GEMM2 + LDS-epilogue LN/tanh/logit (fused, one kernel) ----------------
// y[bt,i] = sum_d x[bt,d]*M1[i,d] + cb[b,i]; LN over i; tanh; logit = h . m2w + m2b
// K-loop identical to R7 k_gemm2s; epilogue = R7 k_lnlogit algorithm with sY := sB (LDS reuse).
__launch_bounds__(512)
__global__ void k_gemm2f(const float* __restrict__ x,
                         const unsigned short* __restrict__ M1bf,
                         const float* __restrict__ cb,
                         const float* __restrict__ lng, const float* __restrict__ lnb,
                         const float* __restrict__ m2w, const float* __restrict__ m2b,
                         float* __restrict__ logits) {
    __shared__ __align__(16) unsigned short sA[64 * 64];
    __shared__ __align__(16) unsigned short sB[512 * 64];   // reused as packed-y after K-loop
    __shared__ float sCb[512], sG[512], sBe[512], sW[512];
    __shared__ float sS1[64][8], sS2[64][8], sLg[64][8];
    int bt0 = blockIdx.x * 64;
    int b = bt0 >> 10;
    int tid = threadIdx.x, lane = tid & 63, w = tid >> 6;
    int wm = w >> 2, wn = w & 3;
    int lo = lane & 15, hi = lane >> 4;
    int lr = lane >> 3, sl = lane & 7;
    // stage epilogue params once (visible after later barriers)
    sCb[tid] = cb[b * 512 + tid];
    sG[tid]  = lng[tid];
    sBe[tid] = lnb[tid];
    sW[tid]  = m2w[tid];
    int arow = tid >> 3, aslot = tid & 7;
    const float* gA = x + (size_t)(bt0 + arow) * 512 + aslot * 8;
    unsigned short* dAp = sA + arow * 64 + ((aslot ^ (arow & 7)) << 3);
    const unsigned short* gB[8];
    #pragma unroll
    for (int g = 0; g < 8; ++g)
        gB[g] = M1bf + (size_t)(w * 64 + g * 8 + lr) * 512 + ((sl ^ lr) << 3);
    f32x4 acc[2][8] = {};
    for (int k0 = 0; k0 < 512; k0 += 64) {
        if (k0) __syncthreads();
        #pragma unroll
        for (int g = 0; g < 8; ++g)
            GLOAD_LDS16(gB[g] + k0, &sB[(w * 64 + g * 8) * 64]);
        float4 f0 = *(const float4*)(gA + k0);
        float4 f1 = *(const float4*)(gA + k0 + 4);
        bf16x8 pk;
        pk[0] = (short)f2bf(f0.x); pk[1] = (short)f2bf(f0.y);
        pk[2] = (short)f2bf(f0.z); pk[3] = (short)f2bf(f0.w);
        pk[4] = (short)f2bf(f1.x); pk[5] = (short)f2bf(f1.y);
        pk[6] = (short)f2bf(f1.z); pk[7] = (short)f2bf(f1.w);
        *(bf16x8*)dAp = pk;
        __syncthreads();
        #pragma unroll
        for (int kk = 0; kk < 2; ++kk) {
            int slotX = ((kk * 4 + hi) ^ (lo & 7)) << 3;
            bf16x8 a0 = *(const bf16x8*)(sA + (wm * 32 +      lo) * 64 + slotX);
            bf16x8 a1 = *(const bf16x8*)(sA + (wm * 32 + 16 + lo) * 64 + slotX);
            #pragma unroll
            for (int n = 0; n < 8; ++n) {
                bf16x8 bb = *(const bf16x8*)(sB + (wn * 128 + n * 16 + lo) * 64 + slotX);
                acc[0][n] = MFMA(a0, bb, acc[0][n]);
                acc[1][n] = MFMA(a1, bb, acc[1][n]);
            }
        }
    }
    __syncthreads();                       // all waves done reading sB
    // pack acc -> bf16 into sB (chunk c = w*16+m*8+n, elem (hi*16+lo)*4+r)
    unsigned short* sY = sB;
    #pragma unroll
    for (int m = 0; m < 2; ++m) {
        #pragma unroll
        for (int n = 0; n < 8; ++n) {
            unsigned int u0 = pk2(acc[m][n][0], acc[m][n][1]);
            unsigned int u1 = pk2(acc[m][n][2], acc[m][n][3]);
            uint2 o; o.x = u0; o.y = u1;
            *(uint2*)(sY + (((w * 16 + m * 8 + n) << 8) + (lane << 2))) = o;
        }
    }
    __syncthreads();
    // LN + tanh + logit (R7 k_lnlogit body)
    int erow = tid >> 3, esub = tid & 7;
    int ewm = erow >> 5, em = (erow >> 4) & 1, ehi = (erow >> 2) & 3, er = erow & 3;
    float s1 = 0.f, s2 = 0.f;
    #pragma unroll
    for (int ewn = 0; ewn < 4; ++ewn) {
        #pragma unroll
        for (int en = 0; en < 8; ++en) {
            int c = (ewm * 4 + ewn) * 16 + em * 8 + en;
            int eb = c * 256 + er;
            int ib = ewn * 128 + en * 16;
            #pragma unroll
            for (int l2 = 0; l2 < 2; ++l2) {
                int elo = esub * 2 + l2;
                float v = bf2f(sY[eb + (ehi * 16 + elo) * 4]) + sCb[ib + elo];
                s1 += v; s2 += v * v;
            }
        }
    }
    sS1[erow][esub] = s1; sS2[erow][esub] = s2;
    __syncthreads();
    float a1 = 0.f, a2 = 0.f;
    #pragma unroll
    for (int q = 0; q < 8; ++q) { a1 += sS1[erow][q]; a2 += sS2[erow][q]; }
    float mu = a1 * (1.0f / 512.0f);
    float var = a2 * (1.0f / 512.0f) - mu * mu;
    float rs = rsqrtf(var + 1e-5f);
    float lg = 0.f;
    #pragma unroll
    for (int ewn = 0; ewn < 4; ++ewn) {
        #pragma unroll
        for (int en = 0; en < 8; ++en) {
            int c = (ewm * 4 + ewn) * 16 + em * 8 + en;
            int eb = c * 256 + er;
            int ib = ewn * 128 + en * 16;
            #pragma unroll
            for (int l2 = 0; l2 < 2; ++l2) {
                int elo = esub * 2 + l2;
                float v = bf2f(sY[eb + (ehi * 16 + elo) * 4]) + sCb[ib + elo];
                float h = tanh_fast((v - mu) * rs * sG[ib + elo] + sBe[ib + elo]);
                lg += h * sW[ib + elo];
            }
        }
    }
    sLg[erow][esub] = lg;
    __syncthreads();
    if (esub == 0) {
        float t = 0.f;
        #pragma unroll
        for (int q = 0; q < 8; ++q) t += sLg[erow][q];
        logits[bt0 + erow] = t + m2b[0];
    }
}

// ---------------- softmax (per-block recompute) + context partials ----------------
// block (b,tc): softmax over logits[b][:] in LDS; tc==0 writes attn out;
// context partial over its 64 t's -> ctxp[(b*16+tc)*512 + d]
__global__ void k_swctx(const float* __restrict__ x, const float* __restrict__ logits,
                        float* __restrict__ ctxp, float* __restrict__ attn) {
    int b = blockIdx.x, tc = blockIdx.y;
    int tid = threadIdx.x;
    __shared__ float red[4];
    __shared__ float sWt[1024];
    float4 v = ((const float4*)(logits + b * 1024))[tid];
    float mx = fmaxf(fmaxf(v.x, v.y), fmaxf(v.z, v.w));
    for (int off = 32; off; off >>= 1) mx = fmaxf(mx, __shfl_xor(mx, off));
    if ((tid & 63) == 0) red[tid >> 6] = mx;
    __syncthreads();
    mx = fmaxf(fmaxf(red[0], red[1]), fmaxf(red[2], red[3]));
    float e0 = expf(v.x - mx), e1 = expf(v.y - mx), e2 = expf(v.z - mx), e3 = expf(v.w - mx);
    float sm = e0 + e1 + e2 + e3;
    for (int off = 32; off; off >>= 1) sm += __shfl_xor(sm, off);
    __syncthreads();
    if ((tid & 63) == 0) red[tid >> 6] = sm;
    __syncthreads();
    float inv = 1.0f / (red[0] + red[1] + red[2] + red[3]);
    float4 o; o.x = e0 * inv; o.y = e1 * inv; o.z = e2 * inv; o.w = e3 * inv;
    ((float4*)sWt)[tid] = o;
    if (tc == 0) ((float4*)(attn + b * 1024))[tid] = o;
    __syncthreads();
    const float* xp = x + ((size_t)b * 1024 + tc * 64) * 512;
    const float* wp = sWt + tc * 64;
    float a0 = 0.f, a1 = 0.f;
    for (int t = 0; t < 64; ++t) {
        float wv = wp[t];
        a0 += wv * xp[(size_t)t * 512 + tid];
        a1 += wv * xp[(size_t)t * 512 + tid + 256];
    }
    float* op = ctxp + (size_t)(b * 16 + tc) * 512;
    op[tid] = a0;
    op[tid + 256] = a1;
}

// context[b][d] = sum of 16 partials
__global__ void k_ctxred(const float* __restrict__ ctxp, float* __restrict__ ctx) {
    int idx = blockIdx.x * 256 + threadIdx.x;   // 8192
    int b = idx >> 9, d = idx & 511;
    float s = 0.f;
    #pragma unroll
    for (int p = 0; p < 16; ++p)
        s += ctxp[(size_t)(b * 16 + p) * 512 + d];
    ctx[b * 512 + d] = s;
}

// ---------------- launch ----------------
extern "C" void kernel_launch(void* const* d_in, const int* in_sizes, int n_in,
                              void* d_out, int out_size, void* d_ws, size_t ws_size,
                              hipStream_t stream) {
    (void)in_sizes; (void)n_in; (void)out_size; (void)ws_size;
    const float* x    = (const float*)d_in[0];
    const float* Went = (const float*)d_in[1];
    const float* bent = (const float*)d_in[2];
    const float* m1w  = (const float*)d_in[3];
    const float* m1b  = (const float*)d_in[4];
    const float* lng  = (const float*)d_in[5];
    const float* lnb  = (const float*)d_in[6];
    const float* m2w  = (const float*)d_in[7];
    const float* m2b  = (const float*)d_in[8];
    float* out = (float*)d_out;            // [0,8192): context ; [8192,24576): attn
    char* ws = (char*)d_ws;

    unsigned short* Abf   = (unsigned short*)(ws);                        // 4 MB
    unsigned short* WT    = (unsigned short*)(ws + 4194304);              // 8 MB
    float* CpL            = (float*)(ws + 12582912);                      // 8 MB
    float* CpR            = (float*)(ws + 20971520);                      // 8 MB
    unsigned short* M1bf  = (unsigned short*)(ws + 29360128);             // 512 KB
    unsigned short* M2t   = (unsigned short*)(ws + 29884416);             // 512 KB
    float* sumxp  = (float*)(ws + 30408704);                              // 512 KB
    float* ctxp   = (float*)(ws + 30932992);                              // 512 KB
    float* bias2  = (float*)(ws + 31457280);                              // 2 KB
    float* cb     = (float*)(ws + 31459328);                              // 32 KB
    float* logits = (float*)(ws + 31492096);                              // 64 KB

    k_sumxp<<<dim3(16, 16), 256, 0, stream>>>(x, sumxp);
    k_prepA<<<512, 256, 0, stream>>>(m1w, bent, Abf, bias2);
    k_conv_W<<<dim3(32, 32), 256, 0, stream>>>(Went, WT);
    k_gemm1<<<dim3(8, 4, 8), 512, 0, stream>>>(Abf, WT, CpL, CpR);
    k_reduce<<<512, 256, 0, stream>>>(CpL, CpR, M1bf, M2t);
    k_cb<<<dim3(16, 8), 256, 0, stream>>>(sumxp, M2t, bias2, m1b, cb);
    k_gemm2f<<<256, 512, 0, stream>>>(x, M1bf, cb, lng, lnb, m2w, m2b, logits);
    k_swctx<<<dim3(16, 16), 256, 0, stream>>>(x, logits, ctxp, out + 8192);
    k_ctxred<<<32, 256, 0, stream>>>(ctxp, out);
}